// Round 5
// baseline (5715.572 us; speedup 1.0000x reference)
//
#include <hip/hip_runtime.h>
#include <stdint.h>

typedef _Float16 f16;
typedef _Float16 h2 __attribute__((ext_vector_type(2)));
typedef float f4 __attribute__((ext_vector_type(4)));

union F4H { f4 v; h2 h[4]; f16 s[8]; };

__device__ __forceinline__ float fdot2(h2 a, h2 b, float c) {
    return __builtin_amdgcn_fdot2(a, b, c, false);
}

#define NB 64
#define NT 512
#define NH 256
#define NG 1024

// ---------------- workspace layout ----------------
static const size_t OFF_H0   = 0;           // h0 f16  [64][512][256]   16,777,216 B
static const size_t OFF_X1   = 16777216;    // xc0/x1 f16 [64*512][1024] 67,108,864 B
static const size_t OFF_H1   = 83886080;    // h1 f16  [64][512][256]   16,777,216 B
static const size_t OFF_PL0  = 100663296;   // packed Whh0 [32][1024] f4  524,288 B
static const size_t OFF_PL1  = 101187584;   // packed Whh1                524,288 B
static const size_t OFF_WIH1 = 101711872;   // packed Wih1 [32][1024] f4  524,288 B
static const size_t OFF_B0C  = 102252544;   // bias0c f32 [1024]            4,096 B
static const size_t OFF_B1C  = 102256640;   // bias1c f32 [1024]            4,096 B
static const size_t OFF_WR1  = 102260736;   // wr1p f4 [32][128]           65,536 B
static const size_t OFF_MM   = 102326272;   // mmean f32 [64][256]         65,536 B
static const size_t OFF_M1S  = 102391808;   // m1sum f32 [64][128]         32,768 B
static const size_t OFF_HL   = 102424576;   // hh1last f32 [64][128]       32,768 B
// cross-WG comm blocks live in DEAD regions (no ws growth):
//   layer-0 comm sits inside the h1 region (h1 written only later, by chain<1>)
//   layer-1 comm sits inside the h0 region (h0 dead after k2 consumed it)
static const size_t OFF_FL0  = OFF_H1 + 8388608;   // flags0 u32 [128][16]   8,192 B
static const size_t OFF_HB0  = OFF_FL0 + 8192;     // hbuf0 f32 [128][2][128] 131,072 B
static const size_t OFF_FL1  = OFF_H0 + 8388608;   // flags1
static const size_t OFF_HB1  = OFF_FL1 + 8192;     // hbuf1

// ---------------- packing kernels (proven) ----------------
__global__ void pack_w256(const float* __restrict__ src, f4* __restrict__ dst)
{
    const int id = blockIdx.x * 256 + threadIdx.x;   // 32768 tasks
    const int j = id >> 5;
    const int g = id & 31;
    const float* s = src + j * 256 + g * 8;
    F4H u;
    #pragma unroll
    for (int i = 0; i < 8; ++i) u.s[i] = (f16)s[i];
    dst[g * 1024 + j] = u.v;
}

__global__ void pack_misc(const float* __restrict__ bih0, const float* __restrict__ bhh0,
                          const float* __restrict__ bih1, const float* __restrict__ bhh1,
                          const float* __restrict__ wr1,
                          float* __restrict__ bias0c, float* __restrict__ bias1c,
                          f4* __restrict__ wr1p)
{
    const int id = blockIdx.x * 256 + threadIdx.x;   // 6144 tasks
    if (id < 1024) {
        bias0c[id] = bih0[id] + bhh0[id];
    } else if (id < 2048) {
        const int j = id - 1024;
        bias1c[j] = bih1[j] + bhh1[j];
    } else {
        const int q = id - 2048;
        const int g = q >> 7, o = q & 127;
        F4H u;
        #pragma unroll
        for (int i = 0; i < 8; ++i)
            u.s[i] = (o < 100) ? (f16)wr1[o * 256 + g * 8 + i] : (f16)0.f;
        wr1p[g * 128 + o] = u.v;
    }
}

// ---------------- K0: xc0 = x @ Wih0^T + bias0 (proven) ----------------
__global__ __launch_bounds__(256)
void k0_xc(const float* __restrict__ x, const float* __restrict__ wih0,
           const float* __restrict__ b0c, f16* __restrict__ xc)
{
    __shared__ float xs[512];
    const int l = threadIdx.x;
    const int r0 = blockIdx.x * 64;
    xs[l]       = x[r0 * 8 + l];
    xs[l + 256] = x[r0 * 8 + l + 256];
    __syncthreads();

    #pragma unroll 1
    for (int pass = 0; pass < 4; ++pass) {
        const int col = pass * 256 + l;
        const f4* wp = (const f4*)(wih0 + col * 8);
        f4 w0 = wp[0], w1 = wp[1];
        float bb = b0c[col];
        #pragma unroll 4
        for (int r = 0; r < 64; ++r) {
            const float* xr = xs + r * 8;
            float acc = bb;
            acc += xr[0] * w0[0] + xr[1] * w0[1] + xr[2] * w0[2] + xr[3] * w0[3];
            acc += xr[4] * w1[0] + xr[5] * w1[1] + xr[6] * w1[2] + xr[7] * w1[3];
            xc[(size_t)(r0 + r) * NG + col] = (f16)acc;
        }
    }
}

// ---------------- LSTM chain: 2 WGs per batch, element-split ----------------
// grid 128: b = bid&63, r = bid>>6 (pair (b,b+64) shares an XCD under bid%8).
// WG r owns h-elements e in [128r,128r+128): gate cols {e, e+256, e+512, e+768}.
// 256 threads: tlo=t&127 -> e = 128r+tlo; th=t>>7 -> cols j0=th*256+e (i|f),
// j1=j0+512 (g|o). k-groups: own half gO=16r..+15, partner gP=16(1-r)..+15.
// Split per half: 9 reg groups + (own 4 / partner 3) LDS + (own 3 / partner 4)
// streamed. Partner h (128 f32) exchanged per step via agent-scope atomics
// (double-buffered by step parity, flag = steps completed). Own-half dots run
// before the spin to hide partner latency.
// LDS ~60 KB (53.4..80 window) -> compiler plans 2 WGs/CU -> 256-VGPR budget.
#define DOT8(wa_, wb_, hh_) { F4H wa_u; wa_u.v = (wa_); F4H wb_u; wb_u.v = (wb_); F4H hh_u; hh_u.v = (hh_); \
    a0  = fdot2(wa_u.h[0], hh_u.h[0], a0 ); a1  = fdot2(wb_u.h[0], hh_u.h[0], a1 ); \
    a0b = fdot2(wa_u.h[1], hh_u.h[1], a0b); a1b = fdot2(wb_u.h[1], hh_u.h[1], a1b); \
    a0  = fdot2(wa_u.h[2], hh_u.h[2], a0 ); a1  = fdot2(wb_u.h[2], hh_u.h[2], a1 ); \
    a0b = fdot2(wa_u.h[3], hh_u.h[3], a0b); a1b = fdot2(wb_u.h[3], hh_u.h[3], a1b); }

template<int LAYER>
__global__ __launch_bounds__(256)
void lstm_chain(const f16* __restrict__ xc,       // [b][t][1024] f16, bias folded
                const f4* __restrict__ pack,      // [32][1024] f4
                f16* __restrict__ hout,
                float* __restrict__ mmean,
                float* __restrict__ hbuf,         // [128 wg][2 slot][128] f32
                unsigned int* __restrict__ flags) // [128 wg][16] u32
{
    __shared__ f4 wlds[7 * 512];                  // 56 KB
    __shared__ float lg[512];                     // 2 KB: i|f|g|o x 128
    __shared__ __align__(16) f16 hsh[256];        // full h vector (both halves)

    const int t = threadIdx.x;
    const int tlo = t & 127;
    const int th = t >> 7;
    const int bid = blockIdx.x;
    const int b = bid & 63;
    const int r = bid >> 6;
    const int e = r * 128 + tlo;
    const int j0 = th * 256 + e;
    const int j1 = j0 + 512;
    const int gO = r * 16;
    const int gP = (1 - r) * 16;

    // LDS weights: slots 0..3 = own groups gO+9..12; slots 4..6 = partner gP+9..11
    #pragma unroll
    for (int s = 0; s < 7; ++s) {
        const int gg = (s < 4) ? (gO + 9 + s) : (gP + 9 + (s - 4));
        wlds[s * 512 + t]       = pack[gg * 1024 + j0];
        wlds[s * 512 + 256 + t] = pack[gg * 1024 + j1];
    }
    // register weights: own gO+0..8, partner gP+0..8  (144 VGPR)
    f4 wrO0[9], wrO1[9], wrP0[9], wrP1[9];
    #pragma unroll
    for (int i = 0; i < 9; ++i) {
        wrO0[i] = pack[(gO + i) * 1024 + j0];
        wrO1[i] = pack[(gO + i) * 1024 + j1];
        wrP0[i] = pack[(gP + i) * 1024 + j0];
        wrP1[i] = pack[(gP + i) * 1024 + j1];
    }
    hsh[t] = (f16)0.f;
    float cst = 0.f, hsum = 0.f;
    __syncthreads();

    const f4* strO = pack + (gO + 13) * 1024;     // own streamed groups 13..15
    const f4* strP = pack + (gP + 12) * 1024;     // partner streamed groups 12..15
    const f16* xb = xc + (size_t)b * NT * NG;
    f16* houtb = hout + (size_t)b * NT * NH;
    float* myhb = hbuf + (size_t)(r * 64 + b) * 256;
    const float* phb = hbuf + (size_t)((1 - r) * 64 + b) * 256;
    unsigned int* myfl = flags + (r * 64 + b) * 16;
    const unsigned int* pfl = flags + ((1 - r) * 64 + b) * 16;

    #pragma unroll 1
    for (int tt = 0; tt < NT; ++tt) {
        // issue streamed weight loads + x contribution early
        f4 sO0[3], sO1[3], sP0[4], sP1[4];
        #pragma unroll
        for (int g = 0; g < 3; ++g) { sO0[g] = strO[g * 1024 + j0]; sO1[g] = strO[g * 1024 + j1]; }
        #pragma unroll
        for (int g = 0; g < 4; ++g) { sP0[g] = strP[g * 1024 + j0]; sP1[g] = strP[g * 1024 + j1]; }
        const f16* xr = xb + (size_t)tt * NG;
        float a0 = (float)xr[j0];
        float a1 = (float)xr[j1];
        float a0b = 0.f, a1b = 0.f;

        const f4* hv4 = (const f4*)hsh;

        // ---- own-half dots (own h from prev step already in hsh) ----
        #pragma unroll
        for (int i = 0; i < 9; ++i) DOT8(wrO0[i], wrO1[i], hv4[gO + i]);
        #pragma unroll
        for (int s = 0; s < 4; ++s) DOT8(wlds[s * 512 + t], wlds[s * 512 + 256 + t], hv4[gO + 9 + s]);
        #pragma unroll
        for (int g = 0; g < 3; ++g) DOT8(sO0[g], sO1[g], hv4[gO + 13 + g]);

        // ---- fetch partner h_{tt-1} ----
        if (tt > 0) {
            if (t < 128) {
                int guard = 0;
                while (__hip_atomic_load(pfl, __ATOMIC_ACQUIRE, __HIP_MEMORY_SCOPE_AGENT) < (unsigned)tt) {
                    __builtin_amdgcn_s_sleep(8);
                    if (++guard > (1 << 27)) break;   // fail fast, never hang
                }
                float v = __hip_atomic_load(phb + (((tt - 1) & 1) << 7) + tlo,
                                            __ATOMIC_RELAXED, __HIP_MEMORY_SCOPE_AGENT);
                hsh[(1 - r) * 128 + tlo] = (f16)v;
            }
            __syncthreads();
        }

        // ---- partner-half dots ----
        #pragma unroll
        for (int i = 0; i < 9; ++i) DOT8(wrP0[i], wrP1[i], hv4[gP + i]);
        #pragma unroll
        for (int s = 0; s < 3; ++s) DOT8(wlds[(4 + s) * 512 + t], wlds[(4 + s) * 512 + 256 + t], hv4[gP + 9 + s]);
        #pragma unroll
        for (int g = 0; g < 4; ++g) DOT8(sP0[g], sP1[g], hv4[gP + 12 + g]);

        // ---- gates exchange + activation ----
        lg[th * 128 + tlo]       = a0 + a0b;   // th0: i, th1: f
        lg[(2 + th) * 128 + tlo] = a1 + a1b;   // th0: g, th1: o
        __syncthreads();

        if (t < 128) {
            float gi = lg[tlo], gf = lg[128 + tlo], gg = lg[256 + tlo], go = lg[384 + tlo];
            float si = 1.f / (1.f + __expf(-gi));
            float sf = 1.f / (1.f + __expf(-gf));
            float so = 1.f / (1.f + __expf(-go));
            float tg = 1.f - 2.f / (__expf(2.f * gg) + 1.f);
            cst = sf * cst + si * tg;
            float thv = 1.f - 2.f / (__expf(2.f * cst) + 1.f);
            float hvl = so * thv;
            hsh[e] = (f16)hvl;
            houtb[(size_t)tt * NH + e] = (f16)hvl;
            __hip_atomic_store(myhb + ((tt & 1) << 7) + tlo, hvl,
                               __ATOMIC_RELAXED, __HIP_MEMORY_SCOPE_AGENT);
            if (LAYER == 1) hsum += hvl;
        }
        __syncthreads();   // drains vmcnt: h stores complete before flag
        if (t == 0) __hip_atomic_store(myfl, (unsigned)(tt + 1),
                                       __ATOMIC_RELEASE, __HIP_MEMORY_SCOPE_AGENT);
    }
    if (LAYER == 1 && t < 128) mmean[b * NH + e] = hsum * (1.f / 512.f);
}

// ---------------- K2: x1 = h0 @ Wih1^T + bias1 (proven) ----------------
__global__ __launch_bounds__(256)
void k2_gemm(const f16* __restrict__ h0, const f4* __restrict__ wih1p,
             const float* __restrict__ b1c, f16* __restrict__ x1)
{
    __shared__ __align__(16) f16 ash[64 * 256];
    const int l = threadIdx.x;
    const size_t m0 = (size_t)blockIdx.x * 64;
    const f4* src = (const f4*)(h0 + m0 * 256);
    f4* dst = (f4*)ash;
    #pragma unroll
    for (int i = 0; i < 8; ++i) dst[l + 256 * i] = src[l + 256 * i];
    __syncthreads();

    const int lane = l & 63;
    const int rg4 = l >> 6;
    #pragma unroll 1
    for (int pass = 0; pass < 16; ++pass) {
        const int rgrp = pass >> 2;
        const int nc = pass & 3;
        const int row0 = rgrp * 16 + rg4 * 4;
        const int col0 = nc * 256 + lane;
        float acc[4][4];
        float bq[4];
        #pragma unroll
        for (int q = 0; q < 4; ++q) bq[q] = b1c[col0 + 64 * q];
        #pragma unroll
        for (int r = 0; r < 4; ++r)
            #pragma unroll
            for (int q = 0; q < 4; ++q) acc[r][q] = bq[q];

        for (int u = 0; u < 32; ++u) {
            f4 wv[4];
            #pragma unroll
            for (int q = 0; q < 4; ++q) wv[q] = wih1p[u * 1024 + col0 + 64 * q];
            #pragma unroll
            for (int r = 0; r < 4; ++r) {
                F4H av; av.v = ((const f4*)ash)[(row0 + r) * 32 + u];
                #pragma unroll
                for (int q = 0; q < 4; ++q) {
                    F4H wq; wq.v = wv[q];
                    #pragma unroll
                    for (int p = 0; p < 4; ++p) acc[r][q] = fdot2(av.h[p], wq.h[p], acc[r][q]);
                }
            }
        }
        #pragma unroll
        for (int r = 0; r < 4; ++r)
            #pragma unroll
            for (int q = 0; q < 4; ++q)
                x1[(m0 + row0 + r) * 1024 + col0 + 64 * q] = (f16)acc[r][q];
    }
}

// ---------------- K4a (proven) ----------------
__global__ __launch_bounds__(256)
void k4a(const f16* __restrict__ h1, const float* __restrict__ mmean,
         const float* __restrict__ Wl1, const float* __restrict__ b1,
         const f4* __restrict__ wr1p, float* __restrict__ m1sum,
         float* __restrict__ hh1last)
{
    __shared__ __align__(16) f16 ash[64 * 256];
    __shared__ float msh[256];
    __shared__ float mbase[128];
    __shared__ float red[256];
    const int l = threadIdx.x;
    const int b = blockIdx.x >> 3;
    const int ch = blockIdx.x & 7;

    const f4* src = (const f4*)(h1 + ((size_t)b * 512 + ch * 64) * 256);
    f4* dst = (f4*)ash;
    #pragma unroll
    for (int i = 0; i < 8; ++i) dst[l + 256 * i] = src[l + 256 * i];
    msh[l] = mmean[b * 256 + l];
    __syncthreads();

    if (l < 128) {
        float acc = 0.f;
        if (l < 100) {
            acc = b1[l];
            const float* wrow = Wl1 + l * 256;
            for (int j = 0; j < 256; ++j) acc += msh[j] * wrow[j];
        }
        mbase[l] = acc;
    }
    __syncthreads();

    const int o = l & 127;
    const int th = l >> 7;
    float sumloc = 0.f;
    float last = 0.f;
    #pragma unroll 1
    for (int it = 0; it < 32; ++it) {
        const int tloc = it * 2 + th;
        float acc = mbase[o];
        const f4* arow = (const f4*)(ash + tloc * 256);
        #pragma unroll
        for (int u = 0; u < 32; ++u) {
            F4H av; av.v = arow[u];
            F4H wv; wv.v = wr1p[u * 128 + o];
            #pragma unroll
            for (int p = 0; p < 4; ++p) acc = fdot2(av.h[p], wv.h[p], acc);
        }
        float e = acc > 0.f ? acc : (__expf(acc) - 1.f);
        sumloc += e;
        if (tloc == 63) last = e;
    }
    red[l] = sumloc;
    __syncthreads();
    if (l < 128) {
        float s = red[l] + red[l + 128];
        if (l < 100) atomicAdd(m1sum + b * 128 + l, s);
    }
    if (ch == 7 && th == 1) hh1last[b * 128 + o] = last;
}

// ---------------- K4b: final head (proven) ----------------
__global__ __launch_bounds__(128)
void k4b(const float* __restrict__ m1sum, const float* __restrict__ hh1last,
         const float* __restrict__ Wl2, const float* __restrict__ Wr2,
         const float* __restrict__ b2,
         const float* __restrict__ Wfc1, const float* __restrict__ bfc1,
         const float* __restrict__ Wfc2, const float* __restrict__ bfc2,
         float* __restrict__ out)
{
    __shared__ float m1s[128];
    __shared__ float hl[128];
    __shared__ float s[128];
    __shared__ float zsh[512];
    const int b = blockIdx.x;
    const int l = threadIdx.x;

    m1s[l] = m1sum[b * 128 + l] * (1.f / 512.f);
    hl[l] = hh1last[b * 128 + l];
    __syncthreads();

    {
        float acc = b2[l];
        const float* wl2r = Wl2 + l * 100;
        const float* wr2r = Wr2 + l * 100;
        for (int j = 0; j < 100; ++j) acc += m1s[j] * wl2r[j] + hl[j] * wr2r[j];
        s[l] = acc;
    }
    __syncthreads();

    #pragma unroll 1
    for (int i = 0; i < 4; ++i) {
        const int idx = l + 128 * i;
        const int k = idx >> 6, o = idx & 63;
        const float* w = Wfc1 + (size_t)(k * 64 + o) * 128;
        float a = bfc1[k * 64 + o];
        for (int d = 0; d < 128; ++d) a += s[d] * w[d];
        zsh[idx] = a > 0.f ? a : 0.f;
    }
    __syncthreads();

    #pragma unroll 1
    for (int i = 0; i < 2; ++i) {
        const int idx = l + 128 * i;
        if (idx < 192) {
            const int k = idx / 24, p = idx % 24;
            const float* w = Wfc2 + (size_t)(k * 24 + p) * 64;
            float a = bfc2[k * 24 + p];
            const float* z = zsh + k * 64;
            for (int d = 0; d < 64; ++d) a += z[d] * w[d];
            out[(size_t)(k * 64 + b) * 24 + p] = a;
        }
    }
}

// ---------------- launch ----------------
extern "C" void kernel_launch(void* const* d_in, const int* in_sizes, int n_in,
                              void* d_out, int out_size, void* d_ws, size_t ws_size,
                              hipStream_t stream)
{
    const float* x    = (const float*)d_in[0];
    const float* Wih0 = (const float*)d_in[1];
    const float* Whh0 = (const float*)d_in[2];
    const float* bih0 = (const float*)d_in[3];
    const float* bhh0 = (const float*)d_in[4];
    const float* Wih1 = (const float*)d_in[5];
    const float* Whh1 = (const float*)d_in[6];
    const float* bih1 = (const float*)d_in[7];
    const float* bhh1 = (const float*)d_in[8];
    const float* Wl1  = (const float*)d_in[9];
    const float* Wr1  = (const float*)d_in[10];
    const float* b1   = (const float*)d_in[11];
    const float* Wl2  = (const float*)d_in[12];
    const float* Wr2  = (const float*)d_in[13];
    const float* b2   = (const float*)d_in[14];
    const float* Wfc1 = (const float*)d_in[15];
    const float* bfc1 = (const float*)d_in[16];
    const float* Wfc2 = (const float*)d_in[17];
    const float* bfc2 = (const float*)d_in[18];

    char* ws = (char*)d_ws;
    f16*   h0f   = (f16*)(ws + OFF_H0);
    f16*   x1f   = (f16*)(ws + OFF_X1);    // xc0 shares this slot (dead before k2)
    f16*   h1f   = (f16*)(ws + OFF_H1);
    f4*    pl0   = (f4*)(ws + OFF_PL0);
    f4*    pl1   = (f4*)(ws + OFF_PL1);
    f4*    wih1p = (f4*)(ws + OFF_WIH1);
    float* b0c   = (float*)(ws + OFF_B0C);
    float* b1c   = (float*)(ws + OFF_B1C);
    f4*    wr1p  = (f4*)(ws + OFF_WR1);
    float* mm    = (float*)(ws + OFF_MM);
    float* m1s   = (float*)(ws + OFF_M1S);
    float* hhl   = (float*)(ws + OFF_HL);
    unsigned int* fl0 = (unsigned int*)(ws + OFF_FL0);
    float*        hb0 = (float*)(ws + OFF_HB0);
    unsigned int* fl1 = (unsigned int*)(ws + OFF_FL1);
    float*        hb1 = (float*)(ws + OFF_HB1);

    pack_w256<<<128, 256, 0, stream>>>(Whh0, pl0);
    pack_w256<<<128, 256, 0, stream>>>(Whh1, pl1);
    pack_w256<<<128, 256, 0, stream>>>(Wih1, wih1p);
    pack_misc<<<24, 256, 0, stream>>>(bih0, bhh0, bih1, bhh1, Wr1, b0c, b1c, wr1p);
    hipMemsetAsync(m1s, 0, 64 * 128 * sizeof(float), stream);
    hipMemsetAsync(fl0, 0, 8192, stream);          // comm<0> lives in (not-yet-written) h1 region

    // xc0 = x @ Wih0^T + b0  (into the X1 slot)
    k0_xc<<<512, 256, 0, stream>>>(x, Wih0, b0c, x1f);
    // layer-0 chain: 2 WGs per batch
    lstm_chain<0><<<128, 256, 0, stream>>>(x1f, pl0, h0f, (float*)nullptr, hb0, fl0);
    // x1 = h0 @ Wih1^T + b1  (consumes h0; overwrites xc0)
    k2_gemm<<<512, 256, 0, stream>>>(h0f, wih1p, b1c, x1f);
    hipMemsetAsync(fl1, 0, 8192, stream);          // comm<1> lives in (now-dead) h0 region
    // layer-1 chain (+ mean over t)
    lstm_chain<1><<<128, 256, 0, stream>>>(x1f, pl1, h1f, mm, hb1, fl1);
    // head
    k4a<<<512, 256, 0, stream>>>(h1f, mm, Wl1, b1, wr1p, m1s, hhl);
    k4b<<<64, 128, 0, stream>>>(m1s, hhl, Wl2, Wr2, b2, Wfc1, bfc1, Wfc2, bfc2, (float*)d_out);
}

// Round 6
// 3284.739 us; speedup vs baseline: 1.7400x; 1.7400x over previous
//
#include <hip/hip_runtime.h>
#include <stdint.h>

typedef _Float16 f16;
typedef _Float16 h2 __attribute__((ext_vector_type(2)));
typedef float f4 __attribute__((ext_vector_type(4)));

union F4H { f4 v; h2 h[4]; f16 s[8]; };

__device__ __forceinline__ float fdot2(h2 a, h2 b, float c) {
    return __builtin_amdgcn_fdot2(a, b, c, false);
}

#define NB 64
#define NT 512
#define NH 256
#define NG 1024

// ---------------- workspace layout (round-1 proven footprint) ----------------
static const size_t OFF_H0   = 0;           // h0 f16  [64][512][256]   16,777,216 B
static const size_t OFF_X1   = 16777216;    // x1 f16  [64*512][1024]   67,108,864 B
static const size_t OFF_H1   = 83886080;    // h1 f16  [64][512][256]   16,777,216 B
static const size_t OFF_PL0  = 100663296;   // packed Whh0 [32][1024] f4  524,288 B
static const size_t OFF_PL1  = 101187584;   // packed Whh1                524,288 B
static const size_t OFF_WIH1 = 101711872;   // packed Wih1 [32][1024] f4  524,288 B
static const size_t OFF_WX0  = 102236160;   // wx0 h2 [4][1024]            16,384 B
static const size_t OFF_B0C  = 102252544;   // bias0c f32 [1024]            4,096 B
static const size_t OFF_B1C  = 102256640;   // bias1c f32 [1024]            4,096 B
static const size_t OFF_WR1  = 102260736;   // wr1p f4 [32][128]           65,536 B
static const size_t OFF_MM   = 102326272;   // mmean f32 [64][256]         65,536 B
static const size_t OFF_M1S  = 102391808;   // m1sum f32 [64][128]         32,768 B
static const size_t OFF_HL   = 102424576;   // hh1last f32 (k4a, AFTER mega)
// pipeline flags ALIAS the hh1last region (dead until k4a): 8 KB
static const size_t OFF_FLG  = OFF_HL;      // u32 [2][64][16] (64-B stride)

// ---------------- packing kernels (proven) ----------------
// [1024][256] f32 row-major -> [32 k-groups][1024 cols] f4 (8 f16 each)
__global__ void pack_w256(const float* __restrict__ src, f4* __restrict__ dst)
{
    const int id = blockIdx.x * 256 + threadIdx.x;   // 32768 tasks
    const int j = id >> 5;
    const int g = id & 31;
    const float* s = src + j * 256 + g * 8;
    F4H u;
    #pragma unroll
    for (int i = 0; i < 8; ++i) u.s[i] = (f16)s[i];
    dst[g * 1024 + j] = u.v;
}

__global__ void pack_misc(const float* __restrict__ bih0, const float* __restrict__ bhh0,
                          const float* __restrict__ bih1, const float* __restrict__ bhh1,
                          const float* __restrict__ wih0, const float* __restrict__ wr1,
                          float* __restrict__ bias0c, float* __restrict__ bias1c,
                          h2* __restrict__ wx0p, f4* __restrict__ wr1p)
{
    const int id = blockIdx.x * 256 + threadIdx.x;   // 10240 tasks
    if (id < 1024) {
        bias0c[id] = bih0[id] + bhh0[id];
    } else if (id < 2048) {
        const int j = id - 1024;
        bias1c[j] = bih1[j] + bhh1[j];
    } else if (id < 6144) {
        const int q = id - 2048;
        const int p = q >> 10, j = q & 1023;
        h2 v; v[0] = (f16)wih0[j * 8 + 2 * p]; v[1] = (f16)wih0[j * 8 + 2 * p + 1];
        wx0p[p * 1024 + j] = v;
    } else {
        const int q = id - 6144;
        const int g = q >> 7, o = q & 127;
        F4H u;
        #pragma unroll
        for (int i = 0; i < 8; ++i)
            u.s[i] = (o < 100) ? (f16)wr1[o * 256 + g * 8 + i] : (f16)0.f;
        wr1p[g * 128 + o] = u.v;
    }
}

// ---------------- mega-kernel: 3-stage wavefront pipeline over t ----------------
// grid 192 x 512 thr, all co-resident (192 < capacity). b = bid & 63 so the three
// roles of a batch share an XCD (bid%8 preserved) -> L2-local flag visibility.
//   role 0: layer-0 chain (x-term in regs), publishes h0_t + flag0 each step
//   role 1: streaming k2: x1_t = h0_t @ Wih1^T + b1, gated on flag0, publishes flag1
//   role 2: layer-1 chain, gated on flag1; writes h1, mmean
// Per-step engine (proven, round-4): k-groups 0-2 LDS, 3-7 regs, 8-31 streamed
// in 8 double-buffered phases of 3. LDS ~60.5 KB -> 2-WG/CU plan -> 128-VGPR budget.
#define DOT8(wa_, wb_, hh_) { F4H wa_u; wa_u.v = (wa_); F4H wb_u; wb_u.v = (wb_); F4H hh_u; hh_u.v = (hh_); \
    a0  = fdot2(wa_u.h[0], hh_u.h[0], a0 ); a1  = fdot2(wb_u.h[0], hh_u.h[0], a1 ); \
    a0b = fdot2(wa_u.h[1], hh_u.h[1], a0b); a1b = fdot2(wb_u.h[1], hh_u.h[1], a1b); \
    a0  = fdot2(wa_u.h[2], hh_u.h[2], a0 ); a1  = fdot2(wb_u.h[2], hh_u.h[2], a1 ); \
    a0b = fdot2(wa_u.h[3], hh_u.h[3], a0b); a1b = fdot2(wb_u.h[3], hh_u.h[3], a1b); }

#define STREAM_PHASES(HV) \
    _Pragma("unroll") \
    for (int p = 0; p < 8; ++p) { \
        if ((p & 1) == 0) { \
            _Pragma("unroll") \
            for (int g = 0; g < 3; ++g) DOT8(pA0[g], pA1[g], (HV)[8 + 3 * p + g]); \
            if (p < 6) { \
                _Pragma("unroll") \
                for (int g = 0; g < 3; ++g) { \
                    pA0[g] = str[((p + 2) * 3 + g) * 1024 + j0]; \
                    pA1[g] = str[((p + 2) * 3 + g) * 1024 + j1]; \
                } \
            } \
        } else { \
            _Pragma("unroll") \
            for (int g = 0; g < 3; ++g) DOT8(pB0[g], pB1[g], (HV)[8 + 3 * p + g]); \
            if (p < 6) { \
                _Pragma("unroll") \
                for (int g = 0; g < 3; ++g) { \
                    pB0[g] = str[((p + 2) * 3 + g) * 1024 + j0]; \
                    pB1[g] = str[((p + 2) * 3 + g) * 1024 + j1]; \
                } \
            } \
        } \
        if (p < 5) DOT8(wrA[p], wrB[p], (HV)[3 + p]); \
    }

__global__ __launch_bounds__(512)
void mega(const float* __restrict__ x,
          const f4* __restrict__ pl0, const f4* __restrict__ pl1,
          const f4* __restrict__ wih1p,
          const float* __restrict__ b0c, const float* __restrict__ b1c,
          const h2* __restrict__ wx0p,
          f16* __restrict__ h0, f16* __restrict__ x1, f16* __restrict__ h1,
          float* __restrict__ mmean, unsigned int* __restrict__ flags)
{
    __shared__ f4 wlds[3 * 1024];                 // 48 KB
    __shared__ float gates[1024];                 // 4 KB
    __shared__ __align__(16) f16 hsh[256];        // 512 B
    __shared__ h2 xsh[512 * 4];                   // 8 KB (role 0 only)

    const int t = threadIdx.x;
    const int bid = blockIdx.x;
    const int role = bid >> 6;
    const int b = bid & 63;
    const int j0 = t, j1 = t + 512;

    const f4* pack = (role == 0) ? pl0 : (role == 1) ? wih1p : pl1;

    #pragma unroll
    for (int i = 0; i < 6; ++i) wlds[t + 512 * i] = pack[t + 512 * i];
    f4 wrA[5], wrB[5];
    #pragma unroll
    for (int g = 0; g < 5; ++g) {
        wrA[g] = pack[(3 + g) * 1024 + j0];
        wrB[g] = pack[(3 + g) * 1024 + j1];
    }
    const f4* str = pack + 8 * 1024;

    if (role == 0) {
        // =================== layer-0 chain (producer) ===================
        const float bc0 = b0c[j0], bc1 = b0c[j1];
        h2 wxA[4], wxB[4];
        #pragma unroll
        for (int p = 0; p < 4; ++p) { wxA[p] = wx0p[p * 1024 + j0]; wxB[p] = wx0p[p * 1024 + j1]; }
        const float* xb = x + ((size_t)b * NT + t) * 8;
        #pragma unroll
        for (int p = 0; p < 4; ++p) {
            h2 v; v[0] = (f16)xb[2 * p]; v[1] = (f16)xb[2 * p + 1];
            xsh[t * 4 + p] = v;
        }
        if (t < 32) { f4 zz = {0.f, 0.f, 0.f, 0.f}; ((f4*)hsh)[t] = zz; }
        float cst = 0.f;
        __syncthreads();

        f16* houtb = h0 + (size_t)b * NT * NH;
        unsigned int* myfl = flags + b * 16;

        #pragma unroll 1
        for (int tt = 0; tt < NT; ++tt) {
            f4 pA0[3], pA1[3], pB0[3], pB1[3];
            #pragma unroll
            for (int g = 0; g < 3; ++g) { pA0[g] = str[g * 1024 + j0]; pA1[g] = str[g * 1024 + j1]; }
            float a0 = bc0, a1 = bc1, a0b = 0.f, a1b = 0.f;
            #pragma unroll
            for (int p = 0; p < 4; ++p) {
                h2 xv = xsh[tt * 4 + p];
                a0 = fdot2(wxA[p], xv, a0);
                a1 = fdot2(wxB[p], xv, a1);
            }
            #pragma unroll
            for (int g = 0; g < 3; ++g) { pB0[g] = str[(3 + g) * 1024 + j0]; pB1[g] = str[(3 + g) * 1024 + j1]; }

            const f4* hv4 = (const f4*)hsh;
            #pragma unroll
            for (int i = 0; i < 3; ++i) DOT8(wlds[i * 1024 + j0], wlds[i * 1024 + j1], hv4[i]);
            STREAM_PHASES(hv4)

            gates[j0] = a0 + a0b;
            gates[j1] = a1 + a1b;
            __syncthreads();

            if (t < 256) {
                float gi = gates[t], gf = gates[t + 256], gg = gates[t + 512], go = gates[t + 768];
                float si = 1.f / (1.f + __expf(-gi));
                float sf = 1.f / (1.f + __expf(-gf));
                float so = 1.f / (1.f + __expf(-go));
                float tg = 1.f - 2.f / (__expf(2.f * gg) + 1.f);
                cst = sf * cst + si * tg;
                float th = 1.f - 2.f / (__expf(2.f * cst) + 1.f);
                float hvl = so * th;
                hsh[t] = (f16)hvl;
                houtb[(size_t)tt * NH + t] = (f16)hvl;
            }
            __syncthreads();   // compiler drains vmcnt before barrier -> h0 visible in L2
            if (t == 0) __hip_atomic_store(myfl, (unsigned)(tt + 1),
                                           __ATOMIC_RELEASE, __HIP_MEMORY_SCOPE_AGENT);
        }
    } else if (role == 1) {
        // =================== streaming k2 (consumer of h0, producer of x1) ===================
        const float bc0 = b1c[j0], bc1 = b1c[j1];
        __syncthreads();
        const f16* h0b = h0 + (size_t)b * NT * NH;
        f16* x1b = x1 + (size_t)b * NT * NG;
        const unsigned int* pfl = flags + b * 16;
        unsigned int* myfl = flags + 1024 + b * 16;
        bool dead = false;

        #pragma unroll 1
        for (int tt = 0; tt < NT; ++tt) {
            f4 pA0[3], pA1[3], pB0[3], pB1[3];
            #pragma unroll
            for (int g = 0; g < 3; ++g) { pA0[g] = str[g * 1024 + j0]; pA1[g] = str[g * 1024 + j1]; }
            #pragma unroll
            for (int g = 0; g < 3; ++g) { pB0[g] = str[(3 + g) * 1024 + j0]; pB1[g] = str[(3 + g) * 1024 + j1]; }

            if (t < 64 && !dead) {
                unsigned int guard = 0;
                while (__hip_atomic_load(pfl, __ATOMIC_ACQUIRE, __HIP_MEMORY_SCOPE_AGENT) <= (unsigned)tt) {
                    __builtin_amdgcn_s_sleep(1);
                    if (++guard > (1u << 20)) { dead = true; break; }
                }
            }
            if (t < 32) ((f4*)hsh)[t] = ((const f4*)(h0b + (size_t)tt * NH))[t];
            __syncthreads();

            float a0 = bc0, a1 = bc1, a0b = 0.f, a1b = 0.f;
            const f4* hv4 = (const f4*)hsh;
            #pragma unroll
            for (int i = 0; i < 3; ++i) DOT8(wlds[i * 1024 + j0], wlds[i * 1024 + j1], hv4[i]);
            STREAM_PHASES(hv4)

            x1b[(size_t)tt * NG + j0] = (f16)(a0 + a0b);
            x1b[(size_t)tt * NG + j1] = (f16)(a1 + a1b);
            __syncthreads();   // drains stores; also keeps hsh stable until all dots done
            if (t == 0) __hip_atomic_store(myfl, (unsigned)(tt + 1),
                                           __ATOMIC_RELEASE, __HIP_MEMORY_SCOPE_AGENT);
        }
    } else {
        // =================== layer-1 chain (consumer of x1) ===================
        if (t < 32) { f4 zz = {0.f, 0.f, 0.f, 0.f}; ((f4*)hsh)[t] = zz; }
        float cst = 0.f, hsum = 0.f;
        __syncthreads();
        const f16* x1b = x1 + (size_t)b * NT * NG;
        f16* houtb = h1 + (size_t)b * NT * NH;
        const unsigned int* pfl = flags + 1024 + b * 16;
        bool dead = false;

        #pragma unroll 1
        for (int tt = 0; tt < NT; ++tt) {
            f4 pA0[3], pA1[3], pB0[3], pB1[3];
            #pragma unroll
            for (int g = 0; g < 3; ++g) { pA0[g] = str[g * 1024 + j0]; pA1[g] = str[g * 1024 + j1]; }
            #pragma unroll
            for (int g = 0; g < 3; ++g) { pB0[g] = str[(3 + g) * 1024 + j0]; pB1[g] = str[(3 + g) * 1024 + j1]; }

            if (!dead) {
                unsigned int guard = 0;
                while (__hip_atomic_load(pfl, __ATOMIC_ACQUIRE, __HIP_MEMORY_SCOPE_AGENT) <= (unsigned)tt) {
                    __builtin_amdgcn_s_sleep(1);
                    if (++guard > (1u << 20)) { dead = true; break; }
                }
            }
            const f16* xr = x1b + (size_t)tt * NG;
            float a0 = (float)xr[j0];
            float a1 = (float)xr[j1];
            float a0b = 0.f, a1b = 0.f;

            const f4* hv4 = (const f4*)hsh;
            #pragma unroll
            for (int i = 0; i < 3; ++i) DOT8(wlds[i * 1024 + j0], wlds[i * 1024 + j1], hv4[i]);
            STREAM_PHASES(hv4)

            gates[j0] = a0 + a0b;
            gates[j1] = a1 + a1b;
            __syncthreads();

            if (t < 256) {
                float gi = gates[t], gf = gates[t + 256], gg = gates[t + 512], go = gates[t + 768];
                float si = 1.f / (1.f + __expf(-gi));
                float sf = 1.f / (1.f + __expf(-gf));
                float so = 1.f / (1.f + __expf(-go));
                float tg = 1.f - 2.f / (__expf(2.f * gg) + 1.f);
                cst = sf * cst + si * tg;
                float th = 1.f - 2.f / (__expf(2.f * cst) + 1.f);
                float hvl = so * th;
                hsh[t] = (f16)hvl;
                houtb[(size_t)tt * NH + t] = (f16)hvl;
                hsum += hvl;
            }
            __syncthreads();
        }
        if (t < 256) mmean[b * NH + t] = hsum * (1.f / 512.f);
    }
}

// ---------------- K4a (proven) ----------------
__global__ __launch_bounds__(256)
void k4a(const f16* __restrict__ h1, const float* __restrict__ mmean,
         const float* __restrict__ Wl1, const float* __restrict__ b1,
         const f4* __restrict__ wr1p, float* __restrict__ m1sum,
         float* __restrict__ hh1last)
{
    __shared__ __align__(16) f16 ash[64 * 256];
    __shared__ float msh[256];
    __shared__ float mbase[128];
    __shared__ float red[256];
    const int l = threadIdx.x;
    const int b = blockIdx.x >> 3;
    const int ch = blockIdx.x & 7;

    const f4* src = (const f4*)(h1 + ((size_t)b * 512 + ch * 64) * 256);
    f4* dst = (f4*)ash;
    #pragma unroll
    for (int i = 0; i < 8; ++i) dst[l + 256 * i] = src[l + 256 * i];
    msh[l] = mmean[b * 256 + l];
    __syncthreads();

    if (l < 128) {
        float acc = 0.f;
        if (l < 100) {
            acc = b1[l];
            const float* wrow = Wl1 + l * 256;
            for (int j = 0; j < 256; ++j) acc += msh[j] * wrow[j];
        }
        mbase[l] = acc;
    }
    __syncthreads();

    const int o = l & 127;
    const int th = l >> 7;
    float sumloc = 0.f;
    float last = 0.f;
    #pragma unroll 1
    for (int it = 0; it < 32; ++it) {
        const int tloc = it * 2 + th;
        float acc = mbase[o];
        const f4* arow = (const f4*)(ash + tloc * 256);
        #pragma unroll
        for (int u = 0; u < 32; ++u) {
            F4H av; av.v = arow[u];
            F4H wv; wv.v = wr1p[u * 128 + o];
            #pragma unroll
            for (int p = 0; p < 4; ++p) acc = fdot2(av.h[p], wv.h[p], acc);
        }
        float e = acc > 0.f ? acc : (__expf(acc) - 1.f);
        sumloc += e;
        if (tloc == 63) last = e;
    }
    red[l] = sumloc;
    __syncthreads();
    if (l < 128) {
        float s = red[l] + red[l + 128];
        if (l < 100) atomicAdd(m1sum + b * 128 + l, s);
    }
    if (ch == 7 && th == 1) hh1last[b * 128 + o] = last;
}

// ---------------- K4b: final head (proven) ----------------
__global__ __launch_bounds__(128)
void k4b(const float* __restrict__ m1sum, const float* __restrict__ hh1last,
         const float* __restrict__ Wl2, const float* __restrict__ Wr2,
         const float* __restrict__ b2,
         const float* __restrict__ Wfc1, const float* __restrict__ bfc1,
         const float* __restrict__ Wfc2, const float* __restrict__ bfc2,
         float* __restrict__ out)
{
    __shared__ float m1s[128];
    __shared__ float hl[128];
    __shared__ float s[128];
    __shared__ float zsh[512];
    const int b = blockIdx.x;
    const int l = threadIdx.x;

    m1s[l] = m1sum[b * 128 + l] * (1.f / 512.f);
    hl[l] = hh1last[b * 128 + l];
    __syncthreads();

    {
        float acc = b2[l];
        const float* wl2r = Wl2 + l * 100;
        const float* wr2r = Wr2 + l * 100;
        for (int j = 0; j < 100; ++j) acc += m1s[j] * wl2r[j] + hl[j] * wr2r[j];
        s[l] = acc;
    }
    __syncthreads();

    #pragma unroll 1
    for (int i = 0; i < 4; ++i) {
        const int idx = l + 128 * i;
        const int k = idx >> 6, o = idx & 63;
        const float* w = Wfc1 + (size_t)(k * 64 + o) * 128;
        float a = bfc1[k * 64 + o];
        for (int d = 0; d < 128; ++d) a += s[d] * w[d];
        zsh[idx] = a > 0.f ? a : 0.f;
    }
    __syncthreads();

    #pragma unroll 1
    for (int i = 0; i < 2; ++i) {
        const int idx = l + 128 * i;
        if (idx < 192) {
            const int k = idx / 24, p = idx % 24;
            const float* w = Wfc2 + (size_t)(k * 24 + p) * 64;
            float a = bfc2[k * 24 + p];
            const float* z = zsh + k * 64;
            for (int d = 0; d < 64; ++d) a += z[d] * w[d];
            out[(size_t)(k * 64 + b) * 24 + p] = a;
        }
    }
}

// ---------------- launch ----------------
extern "C" void kernel_launch(void* const* d_in, const int* in_sizes, int n_in,
                              void* d_out, int out_size, void* d_ws, size_t ws_size,
                              hipStream_t stream)
{
    const float* x    = (const float*)d_in[0];
    const float* Wih0 = (const float*)d_in[1];
    const float* Whh0 = (const float*)d_in[2];
    const float* bih0 = (const float*)d_in[3];
    const float* bhh0 = (const float*)d_in[4];
    const float* Wih1 = (const float*)d_in[5];
    const float* Whh1 = (const float*)d_in[6];
    const float* bih1 = (const float*)d_in[7];
    const float* bhh1 = (const float*)d_in[8];
    const float* Wl1  = (const float*)d_in[9];
    const float* Wr1  = (const float*)d_in[10];
    const float* b1   = (const float*)d_in[11];
    const float* Wl2  = (const float*)d_in[12];
    const float* Wr2  = (const float*)d_in[13];
    const float* b2   = (const float*)d_in[14];
    const float* Wfc1 = (const float*)d_in[15];
    const float* bfc1 = (const float*)d_in[16];
    const float* Wfc2 = (const float*)d_in[17];
    const float* bfc2 = (const float*)d_in[18];

    char* ws = (char*)d_ws;
    f16*   h0f   = (f16*)(ws + OFF_H0);
    f16*   x1f   = (f16*)(ws + OFF_X1);
    f16*   h1f   = (f16*)(ws + OFF_H1);
    f4*    pl0   = (f4*)(ws + OFF_PL0);
    f4*    pl1   = (f4*)(ws + OFF_PL1);
    f4*    wih1p = (f4*)(ws + OFF_WIH1);
    h2*    wx0p  = (h2*)(ws + OFF_WX0);
    float* b0c   = (float*)(ws + OFF_B0C);
    float* b1c   = (float*)(ws + OFF_B1C);
    f4*    wr1p  = (f4*)(ws + OFF_WR1);
    float* mm    = (float*)(ws + OFF_MM);
    float* m1s   = (float*)(ws + OFF_M1S);
    float* hhl   = (float*)(ws + OFF_HL);
    unsigned int* flg = (unsigned int*)(ws + OFF_FLG);

    pack_w256<<<128, 256, 0, stream>>>(Whh0, pl0);
    pack_w256<<<128, 256, 0, stream>>>(Whh1, pl1);
    pack_w256<<<128, 256, 0, stream>>>(Wih1, wih1p);
    pack_misc<<<40, 256, 0, stream>>>(bih0, bhh0, bih1, bhh1, Wih0, Wr1,
                                      b0c, b1c, wx0p, wr1p);
    hipMemsetAsync(m1s, 0, 64 * 128 * sizeof(float), stream);
    hipMemsetAsync(flg, 0, 8192, stream);   // flags alias hh1last region (dead until k4a)

    // pipelined chain0 -> k2 -> chain1, one launch, 192 co-resident WGs
    mega<<<192, 512, 0, stream>>>(x, pl0, pl1, wih1p, b0c, b1c, wx0p,
                                  h0f, x1f, h1f, mm, flg);

    k4a<<<512, 256, 0, stream>>>(h1f, mm, Wl1, b1, wr1p, m1s, hhl);
    k4b<<<64, 128, 0, stream>>>(m1s, hhl, Wl2, Wr2, b2, Wfc1, bfc1, Wfc2, bfc2, (float*)d_out);
}

// Round 7
// 1355.989 us; speedup vs baseline: 4.2151x; 2.4224x over previous
//
#include <hip/hip_runtime.h>
#include <stdint.h>

typedef _Float16 f16;
typedef _Float16 h2 __attribute__((ext_vector_type(2)));
typedef float f4 __attribute__((ext_vector_type(4)));

union F4H { f4 v; h2 h[4]; f16 s[8]; };

__device__ __forceinline__ float fdot2(h2 a, h2 b, float c) {
    return __builtin_amdgcn_fdot2(a, b, c, false);
}

#define NB 64
#define NT 512
#define NH 256
#define NG 1024

// ---------------- workspace layout ----------------
static const size_t OFF_H0   = 0;           // h0 f16  [64][512][256]   16,777,216 B
static const size_t OFF_X1   = 16777216;    // x1 f16  [64*512][1024]   67,108,864 B
static const size_t OFF_H1   = 83886080;    // h1 f16  [64][512][256]   16,777,216 B
static const size_t OFF_PL0  = 100663296;   // packed Whh0 [32][1024] f4  524,288 B
static const size_t OFF_PL1  = 101187584;   // packed Whh1                524,288 B
static const size_t OFF_WIH1 = 101711872;   // packed Wih1 [32][1024] f4  524,288 B
static const size_t OFF_WX0  = 102236160;   // wx0 h2 [4][1024]            16,384 B
static const size_t OFF_B0C  = 102252544;   // bias0c f32 [1024]            4,096 B
static const size_t OFF_B1C  = 102256640;   // bias1c f32 [1024]            4,096 B
static const size_t OFF_WR1  = 102260736;   // wr1p f4 [32][128]           65,536 B
static const size_t OFF_MM   = 102326272;   // mmean f32 [64][256]         65,536 B
static const size_t OFF_M1S  = 102391808;   // m1sum f32 [64][128]         32,768 B
static const size_t OFF_HL   = 102424576;   // hh1last f32 (k4a, AFTER mega)
// pipeline flags ALIAS the hh1last region (dead until k4a): 8 KB
static const size_t OFF_FLG  = OFF_HL;      // u32: [0..1023] role0->1, [1024..2047] role1->2

// ---------------- packing kernels (proven) ----------------
__global__ void pack_w256(const float* __restrict__ src, f4* __restrict__ dst)
{
    const int id = blockIdx.x * 256 + threadIdx.x;   // 32768 tasks
    const int j = id >> 5;
    const int g = id & 31;
    const float* s = src + j * 256 + g * 8;
    F4H u;
    #pragma unroll
    for (int i = 0; i < 8; ++i) u.s[i] = (f16)s[i];
    dst[g * 1024 + j] = u.v;
}

__global__ void pack_misc(const float* __restrict__ bih0, const float* __restrict__ bhh0,
                          const float* __restrict__ bih1, const float* __restrict__ bhh1,
                          const float* __restrict__ wih0, const float* __restrict__ wr1,
                          float* __restrict__ bias0c, float* __restrict__ bias1c,
                          h2* __restrict__ wx0p, f4* __restrict__ wr1p)
{
    const int id = blockIdx.x * 256 + threadIdx.x;   // 10240 tasks
    if (id < 1024) {
        bias0c[id] = bih0[id] + bhh0[id];
    } else if (id < 2048) {
        const int j = id - 1024;
        bias1c[j] = bih1[j] + bhh1[j];
    } else if (id < 6144) {
        const int q = id - 2048;
        const int p = q >> 10, j = q & 1023;
        h2 v; v[0] = (f16)wih0[j * 8 + 2 * p]; v[1] = (f16)wih0[j * 8 + 2 * p + 1];
        wx0p[p * 1024 + j] = v;
    } else {
        const int q = id - 6144;
        const int g = q >> 7, o = q & 127;
        F4H u;
        #pragma unroll
        for (int i = 0; i < 8; ++i)
            u.s[i] = (o < 100) ? (f16)wr1[o * 256 + g * 8 + i] : (f16)0.f;
        wr1p[g * 128 + o] = u.v;
    }
}

// ---------------- mega-kernel: 3-stage pipeline, CHUNKED sync (CH=16) ----------------
// grid 192 x 512 thr, co-resident. b = bid & 63 keeps a batch's three roles on one
// XCD (bid%8 preserved) -> flags/data coherent through that XCD's L2.
//   role 0: layer-0 chain; releases flag0 = tt+1 every 16 steps
//   role 1: chunked GEMM x1 = h0 @ Wih1^T + b1 (weight reuse over 16 rows);
//           releases flag1 = chunks done
//   role 2: layer-1 chain; acquires once per 16-step chunk (one wave spins)
// Chain engine identical to round-4/6 proven: 3 LDS + 5 reg + 24 streamed groups.
#define DOT8(wa_, wb_, hh_) { F4H wa_u; wa_u.v = (wa_); F4H wb_u; wb_u.v = (wb_); F4H hh_u; hh_u.v = (hh_); \
    a0  = fdot2(wa_u.h[0], hh_u.h[0], a0 ); a1  = fdot2(wb_u.h[0], hh_u.h[0], a1 ); \
    a0b = fdot2(wa_u.h[1], hh_u.h[1], a0b); a1b = fdot2(wb_u.h[1], hh_u.h[1], a1b); \
    a0  = fdot2(wa_u.h[2], hh_u.h[2], a0 ); a1  = fdot2(wb_u.h[2], hh_u.h[2], a1 ); \
    a0b = fdot2(wa_u.h[3], hh_u.h[3], a0b); a1b = fdot2(wb_u.h[3], hh_u.h[3], a1b); }

#define STREAM_PHASES(HV) \
    _Pragma("unroll") \
    for (int p = 0; p < 8; ++p) { \
        if ((p & 1) == 0) { \
            _Pragma("unroll") \
            for (int g = 0; g < 3; ++g) DOT8(pA0[g], pA1[g], (HV)[8 + 3 * p + g]); \
            if (p < 6) { \
                _Pragma("unroll") \
                for (int g = 0; g < 3; ++g) { \
                    pA0[g] = str[((p + 2) * 3 + g) * 1024 + j0]; \
                    pA1[g] = str[((p + 2) * 3 + g) * 1024 + j1]; \
                } \
            } \
        } else { \
            _Pragma("unroll") \
            for (int g = 0; g < 3; ++g) DOT8(pB0[g], pB1[g], (HV)[8 + 3 * p + g]); \
            if (p < 6) { \
                _Pragma("unroll") \
                for (int g = 0; g < 3; ++g) { \
                    pB0[g] = str[((p + 2) * 3 + g) * 1024 + j0]; \
                    pB1[g] = str[((p + 2) * 3 + g) * 1024 + j1]; \
                } \
            } \
        } \
        if (p < 5) DOT8(wrA[p], wrB[p], (HV)[3 + p]); \
    }

__global__ __launch_bounds__(512)
void mega(const float* __restrict__ x,
          const f4* __restrict__ pl0, const f4* __restrict__ pl1,
          const f4* __restrict__ wih1p,
          const float* __restrict__ b0c, const float* __restrict__ b1c,
          const h2* __restrict__ wx0p,
          f16* __restrict__ h0, f16* __restrict__ x1, f16* __restrict__ h1,
          float* __restrict__ mmean, unsigned int* __restrict__ flags)
{
    __shared__ f4 wlds[3 * 1024];                 // 48 KB (roles 0,2)
    __shared__ float gates[1024];                 // 4 KB
    __shared__ __align__(16) f16 hsh[256];        // 512 B
    __shared__ __align__(16) h2 xsh[512 * 4];     // 8 KB: role0 x frags; role1 h0 row tile

    const int t = threadIdx.x;
    const int bid = blockIdx.x;
    const int role = bid >> 6;
    const int b = bid & 63;
    const int j0 = t, j1 = t + 512;

    if (role == 0) {
        // =================== layer-0 chain (producer) ===================
        const f4* pack = pl0;
        #pragma unroll
        for (int i = 0; i < 6; ++i) wlds[t + 512 * i] = pack[t + 512 * i];
        f4 wrA[5], wrB[5];
        #pragma unroll
        for (int g = 0; g < 5; ++g) {
            wrA[g] = pack[(3 + g) * 1024 + j0];
            wrB[g] = pack[(3 + g) * 1024 + j1];
        }
        const f4* str = pack + 8 * 1024;

        const float bc0 = b0c[j0], bc1 = b0c[j1];
        h2 wxA[4], wxB[4];
        #pragma unroll
        for (int p = 0; p < 4; ++p) { wxA[p] = wx0p[p * 1024 + j0]; wxB[p] = wx0p[p * 1024 + j1]; }
        const float* xb = x + ((size_t)b * NT + t) * 8;
        #pragma unroll
        for (int p = 0; p < 4; ++p) {
            h2 v; v[0] = (f16)xb[2 * p]; v[1] = (f16)xb[2 * p + 1];
            xsh[t * 4 + p] = v;
        }
        if (t < 32) { f4 zz = {0.f, 0.f, 0.f, 0.f}; ((f4*)hsh)[t] = zz; }
        float cst = 0.f;
        __syncthreads();

        f16* houtb = h0 + (size_t)b * NT * NH;
        unsigned int* myfl = flags + b * 16;

        #pragma unroll 1
        for (int tt = 0; tt < NT; ++tt) {
            f4 pA0[3], pA1[3], pB0[3], pB1[3];
            #pragma unroll
            for (int g = 0; g < 3; ++g) { pA0[g] = str[g * 1024 + j0]; pA1[g] = str[g * 1024 + j1]; }
            float a0 = bc0, a1 = bc1, a0b = 0.f, a1b = 0.f;
            #pragma unroll
            for (int p = 0; p < 4; ++p) {
                h2 xv = xsh[tt * 4 + p];
                a0 = fdot2(wxA[p], xv, a0);
                a1 = fdot2(wxB[p], xv, a1);
            }
            #pragma unroll
            for (int g = 0; g < 3; ++g) { pB0[g] = str[(3 + g) * 1024 + j0]; pB1[g] = str[(3 + g) * 1024 + j1]; }

            const f4* hv4 = (const f4*)hsh;
            #pragma unroll
            for (int i = 0; i < 3; ++i) DOT8(wlds[i * 1024 + j0], wlds[i * 1024 + j1], hv4[i]);
            STREAM_PHASES(hv4)

            gates[j0] = a0 + a0b;
            gates[j1] = a1 + a1b;
            __syncthreads();

            if (t < 256) {
                float gi = gates[t], gf = gates[t + 256], gg = gates[t + 512], go = gates[t + 768];
                float si = 1.f / (1.f + __expf(-gi));
                float sf = 1.f / (1.f + __expf(-gf));
                float so = 1.f / (1.f + __expf(-go));
                float tg = 1.f - 2.f / (__expf(2.f * gg) + 1.f);
                cst = sf * cst + si * tg;
                float th = 1.f - 2.f / (__expf(2.f * cst) + 1.f);
                float hvl = so * th;
                hsh[t] = (f16)hvl;
                houtb[(size_t)tt * NH + t] = (f16)hvl;
            }
            __syncthreads();   // drains vmcnt -> h0 chunk visible before release
            if (t == 0 && ((tt + 1) & 15) == 0)
                __hip_atomic_store(myfl, (unsigned)(tt + 1),
                                   __ATOMIC_RELEASE, __HIP_MEMORY_SCOPE_AGENT);
        }
    } else if (role == 1) {
        // ============ chunked k2 GEMM: x1[16 rows] = h0[16 rows] @ Wih1^T + b1 ============
        const float bc0 = b1c[j0], bc1 = b1c[j1];
        const f16* h0b = h0 + (size_t)b * NT * NH;
        f16* x1b = x1 + (size_t)b * NT * NG;
        const unsigned int* pfl = flags + b * 16;
        unsigned int* myfl = flags + 1024 + b * 16;
        f16* hrows = (f16*)xsh;    // [16][256] f16 = 8 KB
        bool dead = false;

        #pragma unroll 1
        for (int c = 0; c < 32; ++c) {
            if (t < 64 && !dead) {
                unsigned int guard = 0;
                while (__hip_atomic_load(pfl, __ATOMIC_ACQUIRE, __HIP_MEMORY_SCOPE_AGENT)
                       < (unsigned)((c + 1) * 16)) {
                    __builtin_amdgcn_s_sleep(8);
                    if (++guard > (1u << 16)) { dead = true; break; }
                }
            }
            __syncthreads();   // acquire (L1 inv) by wave 0 ordered before all loads below
            {
                const int rr = t >> 5, cc = t & 31;
                ((f4*)hrows)[t] = ((const f4*)(h0b + (size_t)(c * 16 + rr) * NH))[cc];
            }
            __syncthreads();

            float acc0[16], acc1[16];
            #pragma unroll
            for (int r = 0; r < 16; ++r) { acc0[r] = bc0; acc1[r] = bc1; }

            f4 w0 = wih1p[j0], w1 = wih1p[j1];
            #pragma unroll 1
            for (int g = 0; g < 32; ++g) {
                f4 nw0 = w0, nw1 = w1;
                if (g < 31) { nw0 = wih1p[(g + 1) * 1024 + j0]; nw1 = wih1p[(g + 1) * 1024 + j1]; }
                F4H W0; W0.v = w0; F4H W1; W1.v = w1;
                #pragma unroll
                for (int r = 0; r < 16; ++r) {
                    F4H H; H.v = ((const f4*)hrows)[r * 32 + g];
                    acc0[r] = fdot2(W0.h[0], H.h[0], acc0[r]);
                    acc0[r] = fdot2(W0.h[1], H.h[1], acc0[r]);
                    acc0[r] = fdot2(W0.h[2], H.h[2], acc0[r]);
                    acc0[r] = fdot2(W0.h[3], H.h[3], acc0[r]);
                    acc1[r] = fdot2(W1.h[0], H.h[0], acc1[r]);
                    acc1[r] = fdot2(W1.h[1], H.h[1], acc1[r]);
                    acc1[r] = fdot2(W1.h[2], H.h[2], acc1[r]);
                    acc1[r] = fdot2(W1.h[3], H.h[3], acc1[r]);
                }
                w0 = nw0; w1 = nw1;
            }
            #pragma unroll
            for (int r = 0; r < 16; ++r) {
                x1b[(size_t)(c * 16 + r) * NG + j0] = (f16)acc0[r];
                x1b[(size_t)(c * 16 + r) * NG + j1] = (f16)acc1[r];
            }
            __syncthreads();   // drains x1 stores before release
            if (t == 0) __hip_atomic_store(myfl, (unsigned)(c + 1),
                                           __ATOMIC_RELEASE, __HIP_MEMORY_SCOPE_AGENT);
        }
    } else {
        // =================== layer-1 chain (consumer of x1) ===================
        const f4* pack = pl1;
        #pragma unroll
        for (int i = 0; i < 6; ++i) wlds[t + 512 * i] = pack[t + 512 * i];
        f4 wrA[5], wrB[5];
        #pragma unroll
        for (int g = 0; g < 5; ++g) {
            wrA[g] = pack[(3 + g) * 1024 + j0];
            wrB[g] = pack[(3 + g) * 1024 + j1];
        }
        const f4* str = pack + 8 * 1024;

        if (t < 32) { f4 zz = {0.f, 0.f, 0.f, 0.f}; ((f4*)hsh)[t] = zz; }
        float cst = 0.f, hsum = 0.f;
        __syncthreads();
        const f16* x1b = x1 + (size_t)b * NT * NG;
        f16* houtb = h1 + (size_t)b * NT * NH;
        const unsigned int* pfl = flags + 1024 + b * 16;
        bool dead = false;

        #pragma unroll 1
        for (int tt = 0; tt < NT; ++tt) {
            if ((tt & 15) == 0) {                 // chunk-grained acquire, one wave spins
                if (t < 64 && !dead) {
                    unsigned int guard = 0;
                    while (__hip_atomic_load(pfl, __ATOMIC_ACQUIRE, __HIP_MEMORY_SCOPE_AGENT)
                           < (unsigned)((tt >> 4) + 1)) {
                        __builtin_amdgcn_s_sleep(8);
                        if (++guard > (1u << 16)) { dead = true; break; }
                    }
                }
                __syncthreads();
            }

            f4 pA0[3], pA1[3], pB0[3], pB1[3];
            #pragma unroll
            for (int g = 0; g < 3; ++g) { pA0[g] = str[g * 1024 + j0]; pA1[g] = str[g * 1024 + j1]; }
            #pragma unroll
            for (int g = 0; g < 3; ++g) { pB0[g] = str[(3 + g) * 1024 + j0]; pB1[g] = str[(3 + g) * 1024 + j1]; }

            const f16* xr = x1b + (size_t)tt * NG;
            float a0 = (float)xr[j0];
            float a1 = (float)xr[j1];
            float a0b = 0.f, a1b = 0.f;

            const f4* hv4 = (const f4*)hsh;
            #pragma unroll
            for (int i = 0; i < 3; ++i) DOT8(wlds[i * 1024 + j0], wlds[i * 1024 + j1], hv4[i]);
            STREAM_PHASES(hv4)

            gates[j0] = a0 + a0b;
            gates[j1] = a1 + a1b;
            __syncthreads();

            if (t < 256) {
                float gi = gates[t], gf = gates[t + 256], gg = gates[t + 512], go = gates[t + 768];
                float si = 1.f / (1.f + __expf(-gi));
                float sf = 1.f / (1.f + __expf(-gf));
                float so = 1.f / (1.f + __expf(-go));
                float tg = 1.f - 2.f / (__expf(2.f * gg) + 1.f);
                cst = sf * cst + si * tg;
                float th = 1.f - 2.f / (__expf(2.f * cst) + 1.f);
                float hvl = so * th;
                hsh[t] = (f16)hvl;
                houtb[(size_t)tt * NH + t] = (f16)hvl;
                hsum += hvl;
            }
            __syncthreads();
        }
        if (t < 256) mmean[b * NH + t] = hsum * (1.f / 512.f);
    }
}

// ---------------- K4a (proven) ----------------
__global__ __launch_bounds__(256)
void k4a(const f16* __restrict__ h1, const float* __restrict__ mmean,
         const float* __restrict__ Wl1, const float* __restrict__ b1,
         const f4* __restrict__ wr1p, float* __restrict__ m1sum,
         float* __restrict__ hh1last)
{
    __shared__ __align__(16) f16 ash[64 * 256];
    __shared__ float msh[256];
    __shared__ float mbase[128];
    __shared__ float red[256];
    const int l = threadIdx.x;
    const int b = blockIdx.x >> 3;
    const int ch = blockIdx.x & 7;

    const f4* src = (const f4*)(h1 + ((size_t)b * 512 + ch * 64) * 256);
    f4* dst = (f4*)ash;
    #pragma unroll
    for (int i = 0; i < 8; ++i) dst[l + 256 * i] = src[l + 256 * i];
    msh[l] = mmean[b * 256 + l];
    __syncthreads();

    if (l < 128) {
        float acc = 0.f;
        if (l < 100) {
            acc = b1[l];
            const float* wrow = Wl1 + l * 256;
            for (int j = 0; j < 256; ++j) acc += msh[j] * wrow[j];
        }
        mbase[l] = acc;
    }
    __syncthreads();

    const int o = l & 127;
    const int th = l >> 7;
    float sumloc = 0.f;
    float last = 0.f;
    #pragma unroll 1
    for (int it = 0; it < 32; ++it) {
        const int tloc = it * 2 + th;
        float acc = mbase[o];
        const f4* arow = (const f4*)(ash + tloc * 256);
        #pragma unroll
        for (int u = 0; u < 32; ++u) {
            F4H av; av.v = arow[u];
            F4H wv; wv.v = wr1p[u * 128 + o];
            #pragma unroll
            for (int p = 0; p < 4; ++p) acc = fdot2(av.h[p], wv.h[p], acc);
        }
        float e = acc > 0.f ? acc : (__expf(acc) - 1.f);
        sumloc += e;
        if (tloc == 63) last = e;
    }
    red[l] = sumloc;
    __syncthreads();
    if (l < 128) {
        float s = red[l] + red[l + 128];
        if (l < 100) atomicAdd(m1sum + b * 128 + l, s);
    }
    if (ch == 7 && th == 1) hh1last[b * 128 + o] = last;
}

// ---------------- K4b: final head (proven) ----------------
__global__ __launch_bounds__(128)
void k4b(const float* __restrict__ m1sum, const float* __restrict__ hh1last,
         const float* __restrict__ Wl2, const float* __restrict__ Wr2,
         const float* __restrict__ b2,
         const float* __restrict__ Wfc1, const float* __restrict__ bfc1,
         const float* __restrict__ Wfc2, const float* __restrict__ bfc2,
         float* __restrict__ out)
{
    __shared__ float m1s[128];
    __shared__ float hl[128];
    __shared__ float s[128];
    __shared__ float zsh[512];
    const int b = blockIdx.x;
    const int l = threadIdx.x;

    m1s[l] = m1sum[b * 128 + l] * (1.f / 512.f);
    hl[l] = hh1last[b * 128 + l];
    __syncthreads();

    {
        float acc = b2[l];
        const float* wl2r = Wl2 + l * 100;
        const float* wr2r = Wr2 + l * 100;
        for (int j = 0; j < 100; ++j) acc += m1s[j] * wl2r[j] + hl[j] * wr2r[j];
        s[l] = acc;
    }
    __syncthreads();

    #pragma unroll 1
    for (int i = 0; i < 4; ++i) {
        const int idx = l + 128 * i;
        const int k = idx >> 6, o = idx & 63;
        const float* w = Wfc1 + (size_t)(k * 64 + o) * 128;
        float a = bfc1[k * 64 + o];
        for (int d = 0; d < 128; ++d) a += s[d] * w[d];
        zsh[idx] = a > 0.f ? a : 0.f;
    }
    __syncthreads();

    #pragma unroll 1
    for (int i = 0; i < 2; ++i) {
        const int idx = l + 128 * i;
        if (idx < 192) {
            const int k = idx / 24, p = idx % 24;
            const float* w = Wfc2 + (size_t)(k * 24 + p) * 64;
            float a = bfc2[k * 24 + p];
            const float* z = zsh + k * 64;
            for (int d = 0; d < 64; ++d) a += z[d] * w[d];
            out[(size_t)(k * 64 + b) * 24 + p] = a;
        }
    }
}

// ---------------- launch ----------------
extern "C" void kernel_launch(void* const* d_in, const int* in_sizes, int n_in,
                              void* d_out, int out_size, void* d_ws, size_t ws_size,
                              hipStream_t stream)
{
    const float* x    = (const float*)d_in[0];
    const float* Wih0 = (const float*)d_in[1];
    const float* Whh0 = (const float*)d_in[2];
    const float* bih0 = (const float*)d_in[3];
    const float* bhh0 = (const float*)d_in[4];
    const float* Wih1 = (const float*)d_in[5];
    const float* Whh1 = (const float*)d_in[6];
    const float* bih1 = (const float*)d_in[7];
    const float* bhh1 = (const float*)d_in[8];
    const float* Wl1  = (const float*)d_in[9];
    const float* Wr1  = (const float*)d_in[10];
    const float* b1   = (const float*)d_in[11];
    const float* Wl2  = (const float*)d_in[12];
    const float* Wr2  = (const float*)d_in[13];
    const float* b2   = (const float*)d_in[14];
    const float* Wfc1 = (const float*)d_in[15];
    const float* bfc1 = (const float*)d_in[16];
    const float* Wfc2 = (const float*)d_in[17];
    const float* bfc2 = (const float*)d_in[18];

    char* ws = (char*)d_ws;
    f16*   h0f   = (f16*)(ws + OFF_H0);
    f16*   x1f   = (f16*)(ws + OFF_X1);
    f16*   h1f   = (f16*)(ws + OFF_H1);
    f4*    pl0   = (f4*)(ws + OFF_PL0);
    f4*    pl1   = (f4*)(ws + OFF_PL1);
    f4*    wih1p = (f4*)(ws + OFF_WIH1);
    h2*    wx0p  = (h2*)(ws + OFF_WX0);
    float* b0c   = (float*)(ws + OFF_B0C);
    float* b1c   = (float*)(ws + OFF_B1C);
    f4*    wr1p  = (f4*)(ws + OFF_WR1);
    float* mm    = (float*)(ws + OFF_MM);
    float* m1s   = (float*)(ws + OFF_M1S);
    float* hhl   = (float*)(ws + OFF_HL);
    unsigned int* flg = (unsigned int*)(ws + OFF_FLG);

    pack_w256<<<128, 256, 0, stream>>>(Whh0, pl0);
    pack_w256<<<128, 256, 0, stream>>>(Whh1, pl1);
    pack_w256<<<128, 256, 0, stream>>>(Wih1, wih1p);
    pack_misc<<<40, 256, 0, stream>>>(bih0, bhh0, bih1, bhh1, Wih0, Wr1,
                                      b0c, b1c, wx0p, wr1p);
    hipMemsetAsync(m1s, 0, 64 * 128 * sizeof(float), stream);
    hipMemsetAsync(flg, 0, 8192, stream);   // flags alias hh1last region (dead until k4a)

    // pipelined chain0 -> k2 -> chain1, one launch, 192 co-resident WGs
    mega<<<192, 512, 0, stream>>>(x, pl0, pl1, wih1p, b0c, b1c, wx0p,
                                  h0f, x1f, h1f, mm, flg);

    k4a<<<512, 256, 0, stream>>>(h1f, mm, Wl1, b1, wr1p, m1s, hhl);
    k4b<<<64, 128, 0, stream>>>(m1s, hhl, Wl2, Wr2, b2, Wfc1, bfc1, Wfc2, bfc2, (float*)d_out);
}